// Round 19
// baseline (452.534 us; speedup 1.0000x reference)
//
#include <hip/hip_runtime.h>
#include <hip/hip_bf16.h>

constexpr int D_ = 64;
constexpr int NN = 100000;
constexpr int NE = 1600000;
constexpr int RB = 8;        // rows per wave-batch in gemm phase

// ---- sort-CSR parameters
constexpr int BUCK_SH = 7;                         // 128 nodes per bucket
constexpr int NBUCK = (NN + 127) >> BUCK_SH;       // 782
constexpr int NB1 = 256;                           // S1 grid
constexpr int NQ4 = NE / 4;                        // 400000 quads
constexpr int QPB = (NQ4 + NB1 - 1) / NB1;         // 1563 quads/block
constexpr int SCN = NBUCK * NB1;                   // 200192 count entries
constexpr int SCB = (SCN + 1023) / 1024;           // 196 scan blocks

// ---- S1A: per-block LDS histogram of endpoint buckets (no global atomics)
__global__ __launch_bounds__(256) void k_s1count(const int* __restrict__ edges,
                                                 int* __restrict__ cnts) {
  __shared__ int hist[NBUCK];
  for (int i = threadIdx.x; i < NBUCK; i += 256) hist[i] = 0;
  __syncthreads();
  const int q0 = blockIdx.x * QPB;
  const int q1 = min(q0 + QPB, NQ4);
  for (int q = q0 + (int)threadIdx.x; q < q1; q += 256) {
    const int4* ep = reinterpret_cast<const int4*>(edges + 8 * q);
    int4 a = ep[0], b = ep[1];
    atomicAdd(&hist[a.x >> BUCK_SH], 1);
    atomicAdd(&hist[a.y >> BUCK_SH], 1);
    atomicAdd(&hist[a.z >> BUCK_SH], 1);
    atomicAdd(&hist[a.w >> BUCK_SH], 1);
    atomicAdd(&hist[b.x >> BUCK_SH], 1);
    atomicAdd(&hist[b.y >> BUCK_SH], 1);
    atomicAdd(&hist[b.z >> BUCK_SH], 1);
    atomicAdd(&hist[b.w >> BUCK_SH], 1);
  }
  __syncthreads();
  for (int i = threadIdx.x; i < NBUCK; i += 256)
    cnts[i * NB1 + blockIdx.x] = hist[i];  // bucket-major for linear scan
}

// ---- hierarchical scan A (1024-wide blocks)
__global__ __launch_bounds__(1024) void k_scanA(const int* __restrict__ cnt,
                                                int* __restrict__ oscan,
                                                int* __restrict__ bsum, int n) {
  __shared__ int sd[1024];
  const int tid = threadIdx.x;
  const int i = blockIdx.x * 1024 + tid;
  int v = (i < n) ? cnt[i] : 0;
  sd[tid] = v;
  __syncthreads();
  for (int off = 1; off < 1024; off <<= 1) {
    int t = (tid >= off) ? sd[tid - off] : 0;
    __syncthreads();
    sd[tid] += t;
    __syncthreads();
  }
  if (i < n) oscan[i] = sd[tid] - v;
  if (tid == 1023) bsum[blockIdx.x] = sd[1023];
}

// ---- scan B: single 256-thread block scans block totals (exclusive, in place)
__global__ __launch_bounds__(256) void k_scanB(int* __restrict__ bsum, int nb) {
  __shared__ int sd[256];
  const int tid = threadIdx.x;
  int v = (tid < nb) ? bsum[tid] : 0;
  sd[tid] = v;
  __syncthreads();
  for (int off = 1; off < 256; off <<= 1) {
    int t = (tid >= off) ? sd[tid - off] : 0;
    __syncthreads();
    sd[tid] += t;
    __syncthreads();
  }
  if (tid < nb) bsum[tid] = sd[tid] - v;
}

// ---- scan C: add block base
__global__ __launch_bounds__(256) void k_scanC(int* __restrict__ oscan,
                                               const int* __restrict__ bsum, int n) {
  int i = blockIdx.x * 256 + threadIdx.x;
  if (i < n) oscan[i] += bsum[i >> 10];
}

// ---- S1B: scatter items into bucket-sorted array via LDS cursors.
__global__ __launch_bounds__(256) void k_s1scatter(const int* __restrict__ edges,
                                                   const int* __restrict__ sscan,
                                                   unsigned* __restrict__ items) {
  __shared__ int cur[NBUCK];
  for (int i = threadIdx.x; i < NBUCK; i += 256)
    cur[i] = sscan[i * NB1 + blockIdx.x];
  __syncthreads();
  const int q0 = blockIdx.x * QPB;
  const int q1 = min(q0 + QPB, NQ4);
  for (int q = q0 + (int)threadIdx.x; q < q1; q += 256) {
    const int4* ep = reinterpret_cast<const int4*>(edges + 8 * q);
    int4 a = ep[0], b = ep[1];
    int p;
    p = atomicAdd(&cur[a.y >> BUCK_SH], 1); items[p] = ((unsigned)(a.y & 127) << 17) | (unsigned)a.x;
    p = atomicAdd(&cur[a.x >> BUCK_SH], 1); items[p] = ((unsigned)(a.x & 127) << 17) | (unsigned)a.y;
    p = atomicAdd(&cur[a.w >> BUCK_SH], 1); items[p] = ((unsigned)(a.w & 127) << 17) | (unsigned)a.z;
    p = atomicAdd(&cur[a.z >> BUCK_SH], 1); items[p] = ((unsigned)(a.z & 127) << 17) | (unsigned)a.w;
    p = atomicAdd(&cur[b.y >> BUCK_SH], 1); items[p] = ((unsigned)(b.y & 127) << 17) | (unsigned)b.x;
    p = atomicAdd(&cur[b.x >> BUCK_SH], 1); items[p] = ((unsigned)(b.x & 127) << 17) | (unsigned)b.y;
    p = atomicAdd(&cur[b.w >> BUCK_SH], 1); items[p] = ((unsigned)(b.w & 127) << 17) | (unsigned)b.z;
    p = atomicAdd(&cur[b.z >> BUCK_SH], 1); items[p] = ((unsigned)(b.z & 127) << 17) | (unsigned)b.w;
  }
}

// ---- S2: one block per bucket -> local histogram+scan -> offs + nbr placement
__global__ __launch_bounds__(256) void k_s2build(const unsigned* __restrict__ items,
                                                 const int* __restrict__ sscan,
                                                 int* __restrict__ offs,
                                                 int* __restrict__ nbr) {
  const int b = blockIdx.x;
  const int lo = b << BUCK_SH;
  __shared__ int hist[128], scn[128];
  __shared__ int sbase, send;
  if (threadIdx.x == 0) {
    sbase = sscan[b * NB1];
    send = (b + 1 < NBUCK) ? sscan[(b + 1) * NB1] : 2 * NE;
  }
  if (threadIdx.x < 128) hist[threadIdx.x] = 0;
  __syncthreads();
  const int i0 = sbase, i1 = send;
  for (int i = i0 + (int)threadIdx.x; i < i1; i += 256)
    atomicAdd(&hist[items[i] >> 17], 1);
  __syncthreads();
  if (threadIdx.x < 128) scn[threadIdx.x] = hist[threadIdx.x];
  __syncthreads();
  for (int off = 1; off < 128; off <<= 1) {
    int t = (threadIdx.x < 128 && (int)threadIdx.x >= off) ? scn[threadIdx.x - off] : 0;
    __syncthreads();
    if (threadIdx.x < 128) scn[threadIdx.x] += t;
    __syncthreads();
  }
  if (threadIdx.x < 128) {
    int node = lo + threadIdx.x;
    int ex = sbase + scn[threadIdx.x] - hist[threadIdx.x];
    if (node < NN) offs[node] = ex;
    hist[threadIdx.x] = ex;  // placement cursor
  }
  __syncthreads();
  for (int i = i0 + (int)threadIdx.x; i < i1; i += 256) {
    unsigned it = items[i];
    int pos = atomicAdd(&hist[it >> 17], 1);
    nbr[pos] = (int)(it & 0x1FFFFu);
  }
  if (b == 0 && threadIdx.x == 0) offs[NN] = 2 * NE;
}

// W packed: wP[j*68+k] = bf16(W1[k][j])<<16 | bf16(W0[k][j]).
__device__ __forceinline__ void stage_w_pk(const float* __restrict__ W0,
                                           const float* __restrict__ W1,
                                           unsigned* wP) {
  for (int i = threadIdx.x; i < 4096; i += 256) {
    int k = i >> 6, j = i & 63;
    wP[j * 68 + k] = (__float_as_uint(W1[i]) & 0xffff0000u) |
                     (__float_as_uint(W0[i]) >> 16);
  }
}

// fp8 encode: byte0 of cvt_pk_fp8_f32 (HW OCP e4m3 on gfx950)
__device__ __forceinline__ unsigned char f32_to_f8(float v) {
  return (unsigned char)(__builtin_amdgcn_cvt_pk_fp8_f32(v, v, 0, false) & 0xff);
}

// ---- 4-row concurrent quad-fp8 gather. lane = q*16+c (q=slot, c=dword).
// Each while-iteration issues 4 rows x (4 idx + 4 row-loads) = 32 loads in
// flight (4x the per-row-serial version). All row guards are wave-uniform.
// All arrays indexed only by fully-unrolled loops (rule #20).
__device__ __forceinline__ void gather4(const unsigned* __restrict__ msgu,
                                        const int* __restrict__ nbr,
                                        const int* __restrict__ offs,
                                        int rbase, int rclamp,
                                        int q, int c, int lane,
                                        float* __restrict__ val,
                                        float* __restrict__ rdeg) {
  int n1[4], jb[4];
#pragma unroll
  for (int i = 0; i < 4; ++i) {
    int r = min(rbase + i, rclamp);
    jb[i] = offs[r];
    n1[i] = offs[r + 1];
    rdeg[i] = 1.0f / fmaxf((float)(n1[i] - jb[i]), 1.0f);
  }
  float acc[4][4];
#pragma unroll
  for (int i = 0; i < 4; ++i)
#pragma unroll
    for (int k = 0; k < 4; ++k) acc[i][k] = 0.0f;
  bool any = (jb[0] < n1[0]) | (jb[1] < n1[1]) | (jb[2] < n1[2]) | (jb[3] < n1[3]);
  while (any) {
    unsigned mv[4][4];
#pragma unroll
    for (int i = 0; i < 4; ++i) {
      if (jb[i] < n1[i]) {  // wave-uniform
#pragma unroll
        for (int u = 0; u < 4; ++u) {
          int id = nbr[min(jb[i] + 4 * u + q, n1[i] - 1)];  // clamped: hot line
          mv[i][u] = msgu[(id << 4) + c];
        }
      }
    }
#pragma unroll
    for (int i = 0; i < 4; ++i) {
      if (jb[i] < n1[i]) {
#pragma unroll
        for (int u = 0; u < 4; ++u) {
          unsigned m = (jb[i] + 4 * u + q < n1[i]) ? mv[i][u] : 0u;
          auto lo = __builtin_amdgcn_cvt_pk_f32_fp8(m, false);
          auto hi = __builtin_amdgcn_cvt_pk_f32_fp8(m, true);
          acc[i][0] += lo[0]; acc[i][1] += lo[1];
          acc[i][2] += hi[0]; acc[i][3] += hi[1];
        }
      }
    }
    any = false;
#pragma unroll
    for (int i = 0; i < 4; ++i) { jb[i] += 16; any = any | (jb[i] < n1[i]); }
  }
  // q-reduce: 4 rows interleaved (ILP 4 on the shfl chains)
#pragma unroll
  for (int i = 0; i < 4; ++i)
#pragma unroll
    for (int k = 0; k < 4; ++k) {
      acc[i][k] += __shfl_xor(acc[i][k], 16, 64);
      acc[i][k] += __shfl_xor(acc[i][k], 32, 64);
    }
#pragma unroll
  for (int i = 0; i < 4; ++i) {
    float t0 = __shfl(acc[i][0], lane >> 2, 64);
    float t1 = __shfl(acc[i][1], lane >> 2, 64);
    float t2 = __shfl(acc[i][2], lane >> 2, 64);
    float t3 = __shfl(acc[i][3], lane >> 2, 64);
    const int s = lane & 3;
    val[i] = (s == 0) ? t0 : ((s == 1) ? t1 : ((s == 2) ? t2 : t3));
  }
}

// ---- gemm core on a parked 8-row LDS batch, packed bf16 W pair in LDS
__device__ __forceinline__ void gemm_batch(const unsigned* wP,
                                           const float* myrows, int lane,
                                           float bv0, float bv1,
                                           float* a0, float* a1) {
#pragma unroll
  for (int rr = 0; rr < RB; ++rr) { a0[rr] = bv0; a1[rr] = bv1; }
#pragma unroll 1  // rolled: keeps W reads in LDS (no LICM VGPR blowup, R8/R9)
  for (int k4 = 0; k4 < 16; ++k4) {
    uint4 up = *reinterpret_cast<const uint4*>(&wP[lane * 68 + k4 * 4]);
    const float v0x = __uint_as_float(up.x << 16);
    const float v1x = __uint_as_float(up.x & 0xffff0000u);
    const float v0y = __uint_as_float(up.y << 16);
    const float v1y = __uint_as_float(up.y & 0xffff0000u);
    const float v0z = __uint_as_float(up.z << 16);
    const float v1z = __uint_as_float(up.z & 0xffff0000u);
    const float v0w = __uint_as_float(up.w << 16);
    const float v1w = __uint_as_float(up.w & 0xffff0000u);
#pragma unroll
    for (int rr = 0; rr < RB; ++rr) {
      float4 hv = *reinterpret_cast<const float4*>(&myrows[rr * 64 + k4 * 4]);
      a0[rr] = fmaf(hv.x, v0x, a0[rr]); a1[rr] = fmaf(hv.x, v1x, a1[rr]);
      a0[rr] = fmaf(hv.y, v0y, a0[rr]); a1[rr] = fmaf(hv.y, v1y, a1[rr]);
      a0[rr] = fmaf(hv.z, v0z, a0[rr]); a1[rr] = fmaf(hv.z, v1z, a1[rr]);
      a0[rr] = fmaf(hv.w, v0w, a0[rr]); a1[rr] = fmaf(hv.w, v1w, a1[rr]);
    }
  }
}

// ---- gemm2: base = h@W0+b0 (f32), msg = fp8(h@W1+b1). (layer 0 only)
__global__ __launch_bounds__(256) void k_gemm2(
    const float* __restrict__ h, const float* __restrict__ W0,
    const float* __restrict__ b0, const float* __restrict__ W1,
    const float* __restrict__ b1, float* __restrict__ base,
    unsigned char* __restrict__ msg, int nrows) {
  __shared__ unsigned wP[64 * 68];
  __shared__ float rbuf[4][RB * 64];
  stage_w_pk(W0, W1, wP);
  __syncthreads();
  const int lane = threadIdx.x & 63;
  const int wv = threadIdx.x >> 6;
  const int wid = (blockIdx.x * 256 + threadIdx.x) >> 6;
  const int nw = (gridDim.x * 256) >> 6;
  const float bv0 = b0[lane], bv1 = b1[lane];
  float* myrows = rbuf[wv];

  const int chunk = (nrows + nw - 1) / nw;
  const int r0 = wid * chunk;
  const int r1 = min(r0 + chunk, nrows);
  if (r0 >= nrows) return;

  float st[RB];
#pragma unroll
  for (int rr = 0; rr < RB; ++rr) {
    int r = min(r0 + rr, nrows - 1);
    st[rr] = h[(size_t)r * 64 + lane];
  }
  for (int rb = r0; rb < r1; rb += RB) {
#pragma unroll
    for (int rr = 0; rr < RB; ++rr) myrows[rr * 64 + lane] = st[rr];
    const int nb = rb + RB;
    if (nb < r1) {
#pragma unroll
      for (int rr = 0; rr < RB; ++rr) {
        int r = min(nb + rr, nrows - 1);
        st[rr] = h[(size_t)r * 64 + lane];
      }
    }
    float a0[RB], a1[RB];
    gemm_batch(wP, myrows, lane, bv0, bv1, a0, a1);
#pragma unroll
    for (int rr = 0; rr < RB; ++rr) {
      int r = rb + rr;
      if (r < r1) {
        base[(size_t)r * 64 + lane] = a0[rr];
        msg[(size_t)r * 64 + lane] = f32_to_f8(a1[rr]);
      }
    }
  }
}

// ---- fused: agg(l) [+LN+ReLU] then gemm2(l+1); 4-row concurrent gather.
__global__ __launch_bounds__(256) void k_fused(
    float* __restrict__ base, const unsigned char* __restrict__ msgin,
    unsigned char* __restrict__ msgout,
    const int* __restrict__ offs, const int* __restrict__ nbr,
    const float* __restrict__ gamma, const float* __restrict__ beta,
    const float* __restrict__ W0n, const float* __restrict__ b0n,
    const float* __restrict__ W1n, const float* __restrict__ b1n, int nrows) {
  __shared__ unsigned wP[64 * 68];
  __shared__ float rbuf[4][RB * 64];
  stage_w_pk(W0n, W1n, wP);
  __syncthreads();
  const int lane = threadIdx.x & 63;
  const int wv = threadIdx.x >> 6;
  const int q = lane >> 4;
  const int c = lane & 15;
  const int wid = (blockIdx.x * 256 + threadIdx.x) >> 6;
  const int nw = (gridDim.x * 256) >> 6;
  const float gm = gamma[lane], bt = beta[lane];
  const float bv0 = b0n[lane], bv1 = b1n[lane];
  float* myrows = rbuf[wv];
  const unsigned* msgu = reinterpret_cast<const unsigned*>(msgin);

  const int chunk = (nrows + nw - 1) / nw;
  const int r0 = wid * chunk;
  const int r1 = min(r0 + chunk, nrows);
  if (r0 >= nrows) return;

  for (int rb = r0; rb < r1; rb += RB) {
#pragma unroll
    for (int g = 0; g < 2; ++g) {  // two groups of 4 rows
      const int gb = rb + g * 4;
      float bv4[4];
#pragma unroll
      for (int i = 0; i < 4; ++i)  // issue base loads before gather (overlap)
        bv4[i] = base[(size_t)min(gb + i, nrows - 1) * 64 + lane];
      float v4[4], rd4[4];
      gather4(msgu, nbr, offs, gb, nrows - 1, q, c, lane, v4, rd4);
      float vals[4];
#pragma unroll
      for (int i = 0; i < 4; ++i) vals[i] = fmaf(v4[i], rd4[i], bv4[i]);
      // LN x4 interleaved (E[x^2]-mu^2, two trees per row, ILP 8)
      float sA[4], sB[4];
#pragma unroll
      for (int i = 0; i < 4; ++i) { sA[i] = vals[i]; sB[i] = vals[i] * vals[i]; }
#pragma unroll
      for (int off = 32; off > 0; off >>= 1) {
#pragma unroll
        for (int i = 0; i < 4; ++i) {
          sA[i] += __shfl_xor(sA[i], off, 64);
          sB[i] += __shfl_xor(sB[i], off, 64);
        }
      }
#pragma unroll
      for (int i = 0; i < 4; ++i) {
        const float mu = sA[i] * (1.0f / 64.0f);
        const float var = fmaxf(sB[i] * (1.0f / 64.0f) - mu * mu, 0.0f);
        const float dv = vals[i] - mu;
        const float o = fmaxf(fmaf(dv * rsqrtf(var + 1e-5f), gm, bt), 0.0f);
        myrows[(g * 4 + i) * 64 + lane] = o;
      }
    }
    float a0[RB], a1[RB];
    gemm_batch(wP, myrows, lane, bv0, bv1, a0, a1);
#pragma unroll
    for (int rr = 0; rr < RB; ++rr) {
      int r = rb + rr;
      if (r < r1) {
        base[(size_t)r * 64 + lane] = a0[rr];
        msgout[(size_t)r * 64 + lane] = f32_to_f8(a1[rr]);
      }
    }
  }
}

// ---- final aggregation (layer 2, no LN): base += gather(msg)/deg, in place
__global__ __launch_bounds__(256) void k_aggF(
    float* __restrict__ base, const unsigned char* __restrict__ msg,
    const int* __restrict__ offs, const int* __restrict__ nbr, int nrows) {
  const int lane = threadIdx.x & 63;
  const int q = lane >> 4;
  const int c = lane & 15;
  const int wid = (blockIdx.x * 256 + threadIdx.x) >> 6;
  const int nw = (gridDim.x * 256) >> 6;
  const unsigned* msgu = reinterpret_cast<const unsigned*>(msg);
  const int chunk = (((nrows + nw - 1) / nw) + 3) & ~3;  // multiple of 4
  const int r0 = wid * chunk;
  const int r1 = min(r0 + chunk, nrows);
  if (r0 >= nrows) return;
  for (int rb = r0; rb < r1; rb += 4) {
    float bv4[4];
#pragma unroll
    for (int i = 0; i < 4; ++i)
      bv4[i] = base[(size_t)min(rb + i, nrows - 1) * 64 + lane];
    float v4[4], rd4[4];
    gather4(msgu, nbr, offs, rb, nrows - 1, q, c, lane, v4, rd4);
#pragma unroll
    for (int i = 0; i < 4; ++i) {
      int r = rb + i;
      if (r < r1)
        base[(size_t)r * 64 + lane] = fmaf(v4[i], rd4[i], bv4[i]);
    }
  }
}

extern "C" void kernel_launch(void* const* d_in, const int* in_sizes, int n_in,
                              void* d_out, int out_size, void* d_ws, size_t ws_size,
                              hipStream_t stream) {
  const float* vert = (const float*)d_in[0];
  const int* edges = (const int*)d_in[1];
  const float* W0 = (const float*)d_in[2];
  const float* b0 = (const float*)d_in[3];
  const float* W1 = (const float*)d_in[4];
  const float* b1 = (const float*)d_in[5];
  const float* lng = (const float*)d_in[6];
  const float* lnb = (const float*)d_in[7];
  float* base = (float*)d_out;  // base lives in d_out all layers (in-place updates)

  // ws layout: nbr 12.8 | creg 12.8 (items during CSR build; then msgA 6.4 + msgB 6.4) | offs
  const size_t NBR_B = (size_t)2 * NE * 4;        // 12.8 MB
  const size_t MSG_B = (size_t)NN * 64;           // 6.4 MB (fp8)
  int* nbr = (int*)d_ws;
  char* creg = (char*)d_ws + NBR_B;
  unsigned* items = (unsigned*)creg;              // 2*NE u32 = 12.8 MB
  unsigned char* msgA = (unsigned char*)creg;     // 6.4 MB
  unsigned char* msgB = (unsigned char*)(creg + MSG_B);  // 6.4 MB
  int* offs = (int*)(creg + NBR_B);               // persistent, NN+1 ints
  // CSR scan temporaries in d_out (dead before gemm2-L0 writes base)
  int* cnts = (int*)d_out;        // SCN ints
  int* sscan = cnts + SCN;        // SCN ints
  int* bsum = sscan + SCN;        // SCB ints

  // ---- CSR build: bucket sort, zero global atomics
  k_s1count<<<NB1, 256, 0, stream>>>(edges, cnts);
  k_scanA<<<SCB, 1024, 0, stream>>>(cnts, sscan, bsum, SCN);
  k_scanB<<<1, 256, 0, stream>>>(bsum, SCB);
  k_scanC<<<(SCN + 255) / 256, 256, 0, stream>>>(sscan, bsum, SCN);
  k_s1scatter<<<NB1, 256, 0, stream>>>(edges, sscan, items);
  k_s2build<<<NBUCK, 256, 0, stream>>>(items, sscan, offs, nbr);

  const int GG = 1536;   // gemm2 grid
  const int GF = 1536;   // fused grid (25.6 KB LDS -> 6 blocks/CU)
  const int GA = 2048;   // final agg grid

  // layer 0 gemms: vert -> base(d_out), msgA
  k_gemm2<<<GG, 256, 0, stream>>>(vert, W0, b0, W1, b1, base, msgA, NN);
  // fused agg(0)+LN0+gemm(1): base,msgA -> base,msgB
  k_fused<<<GF, 256, 0, stream>>>(base, msgA, msgB, offs, nbr,
                                  lng, lnb, W0 + 4096, b0 + 64,
                                  W1 + 4096, b1 + 64, NN);
  // fused agg(1)+LN1+gemm(2): base,msgB -> base,msgA
  k_fused<<<GF, 256, 0, stream>>>(base, msgB, msgA, offs, nbr,
                                  lng + 64, lnb + 64, W0 + 8192, b0 + 128,
                                  W1 + 8192, b1 + 128, NN);
  // final agg(2), no LN: base += gather(msgA)/deg  (in place -> d_out)
  k_aggF<<<GA, 256, 0, stream>>>(base, msgA, offs, nbr, NN);
}

// Round 20
// 372.569 us; speedup vs baseline: 1.2146x; 1.2146x over previous
//
#include <hip/hip_runtime.h>
#include <hip/hip_bf16.h>

constexpr int D_ = 64;
constexpr int NN = 100000;
constexpr int NE = 1600000;
constexpr int RB = 8;        // rows per wave-batch in gemm phase

// ---- sort-CSR parameters
constexpr int BUCK_SH = 7;                         // 128 nodes per bucket
constexpr int NBUCK = (NN + 127) >> BUCK_SH;       // 782
constexpr int NB1 = 256;                           // S1 grid
constexpr int NQ4 = NE / 4;                        // 400000 quads
constexpr int QPB = (NQ4 + NB1 - 1) / NB1;         // 1563 quads/block
constexpr int SCN = NBUCK * NB1;                   // 200192 count entries
constexpr int SCB = (SCN + 1023) / 1024;           // 196 scan blocks

// ---- S1A: per-block LDS histogram of endpoint buckets (no global atomics)
__global__ __launch_bounds__(256) void k_s1count(const int* __restrict__ edges,
                                                 int* __restrict__ cnts) {
  __shared__ int hist[NBUCK];
  for (int i = threadIdx.x; i < NBUCK; i += 256) hist[i] = 0;
  __syncthreads();
  const int q0 = blockIdx.x * QPB;
  const int q1 = min(q0 + QPB, NQ4);
  for (int q = q0 + (int)threadIdx.x; q < q1; q += 256) {
    const int4* ep = reinterpret_cast<const int4*>(edges + 8 * q);
    int4 a = ep[0], b = ep[1];
    atomicAdd(&hist[a.x >> BUCK_SH], 1);
    atomicAdd(&hist[a.y >> BUCK_SH], 1);
    atomicAdd(&hist[a.z >> BUCK_SH], 1);
    atomicAdd(&hist[a.w >> BUCK_SH], 1);
    atomicAdd(&hist[b.x >> BUCK_SH], 1);
    atomicAdd(&hist[b.y >> BUCK_SH], 1);
    atomicAdd(&hist[b.z >> BUCK_SH], 1);
    atomicAdd(&hist[b.w >> BUCK_SH], 1);
  }
  __syncthreads();
  for (int i = threadIdx.x; i < NBUCK; i += 256)
    cnts[i * NB1 + blockIdx.x] = hist[i];  // bucket-major for linear scan
}

// ---- hierarchical scan A (1024-wide blocks)
__global__ __launch_bounds__(1024) void k_scanA(const int* __restrict__ cnt,
                                                int* __restrict__ oscan,
                                                int* __restrict__ bsum, int n) {
  __shared__ int sd[1024];
  const int tid = threadIdx.x;
  const int i = blockIdx.x * 1024 + tid;
  int v = (i < n) ? cnt[i] : 0;
  sd[tid] = v;
  __syncthreads();
  for (int off = 1; off < 1024; off <<= 1) {
    int t = (tid >= off) ? sd[tid - off] : 0;
    __syncthreads();
    sd[tid] += t;
    __syncthreads();
  }
  if (i < n) oscan[i] = sd[tid] - v;
  if (tid == 1023) bsum[blockIdx.x] = sd[1023];
}

// ---- scan B: single 256-thread block scans block totals (exclusive, in place)
__global__ __launch_bounds__(256) void k_scanB(int* __restrict__ bsum, int nb) {
  __shared__ int sd[256];
  const int tid = threadIdx.x;
  int v = (tid < nb) ? bsum[tid] : 0;
  sd[tid] = v;
  __syncthreads();
  for (int off = 1; off < 256; off <<= 1) {
    int t = (tid >= off) ? sd[tid - off] : 0;
    __syncthreads();
    sd[tid] += t;
    __syncthreads();
  }
  if (tid < nb) bsum[tid] = sd[tid] - v;
}

// ---- scan C: add block base
__global__ __launch_bounds__(256) void k_scanC(int* __restrict__ oscan,
                                               const int* __restrict__ bsum, int n) {
  int i = blockIdx.x * 256 + threadIdx.x;
  if (i < n) oscan[i] += bsum[i >> 10];
}

// ---- S1B: scatter items into bucket-sorted array via LDS cursors.
__global__ __launch_bounds__(256) void k_s1scatter(const int* __restrict__ edges,
                                                   const int* __restrict__ sscan,
                                                   unsigned* __restrict__ items) {
  __shared__ int cur[NBUCK];
  for (int i = threadIdx.x; i < NBUCK; i += 256)
    cur[i] = sscan[i * NB1 + blockIdx.x];
  __syncthreads();
  const int q0 = blockIdx.x * QPB;
  const int q1 = min(q0 + QPB, NQ4);
  for (int q = q0 + (int)threadIdx.x; q < q1; q += 256) {
    const int4* ep = reinterpret_cast<const int4*>(edges + 8 * q);
    int4 a = ep[0], b = ep[1];
    int p;
    p = atomicAdd(&cur[a.y >> BUCK_SH], 1); items[p] = ((unsigned)(a.y & 127) << 17) | (unsigned)a.x;
    p = atomicAdd(&cur[a.x >> BUCK_SH], 1); items[p] = ((unsigned)(a.x & 127) << 17) | (unsigned)a.y;
    p = atomicAdd(&cur[a.w >> BUCK_SH], 1); items[p] = ((unsigned)(a.w & 127) << 17) | (unsigned)a.z;
    p = atomicAdd(&cur[a.z >> BUCK_SH], 1); items[p] = ((unsigned)(a.z & 127) << 17) | (unsigned)a.w;
    p = atomicAdd(&cur[b.y >> BUCK_SH], 1); items[p] = ((unsigned)(b.y & 127) << 17) | (unsigned)b.x;
    p = atomicAdd(&cur[b.x >> BUCK_SH], 1); items[p] = ((unsigned)(b.x & 127) << 17) | (unsigned)b.y;
    p = atomicAdd(&cur[b.w >> BUCK_SH], 1); items[p] = ((unsigned)(b.w & 127) << 17) | (unsigned)b.z;
    p = atomicAdd(&cur[b.z >> BUCK_SH], 1); items[p] = ((unsigned)(b.z & 127) << 17) | (unsigned)b.w;
  }
}

// ---- S2: one block per bucket -> local histogram+scan -> offs + nbr placement
__global__ __launch_bounds__(256) void k_s2build(const unsigned* __restrict__ items,
                                                 const int* __restrict__ sscan,
                                                 int* __restrict__ offs,
                                                 int* __restrict__ nbr) {
  const int b = blockIdx.x;
  const int lo = b << BUCK_SH;
  __shared__ int hist[128], scn[128];
  __shared__ int sbase, send;
  if (threadIdx.x == 0) {
    sbase = sscan[b * NB1];
    send = (b + 1 < NBUCK) ? sscan[(b + 1) * NB1] : 2 * NE;
  }
  if (threadIdx.x < 128) hist[threadIdx.x] = 0;
  __syncthreads();
  const int i0 = sbase, i1 = send;
  for (int i = i0 + (int)threadIdx.x; i < i1; i += 256)
    atomicAdd(&hist[items[i] >> 17], 1);
  __syncthreads();
  if (threadIdx.x < 128) scn[threadIdx.x] = hist[threadIdx.x];
  __syncthreads();
  for (int off = 1; off < 128; off <<= 1) {
    int t = (threadIdx.x < 128 && (int)threadIdx.x >= off) ? scn[threadIdx.x - off] : 0;
    __syncthreads();
    if (threadIdx.x < 128) scn[threadIdx.x] += t;
    __syncthreads();
  }
  if (threadIdx.x < 128) {
    int node = lo + threadIdx.x;
    int ex = sbase + scn[threadIdx.x] - hist[threadIdx.x];
    if (node < NN) offs[node] = ex;
    hist[threadIdx.x] = ex;  // placement cursor
  }
  __syncthreads();
  for (int i = i0 + (int)threadIdx.x; i < i1; i += 256) {
    unsigned it = items[i];
    int pos = atomicAdd(&hist[it >> 17], 1);
    nbr[pos] = (int)(it & 0x1FFFFu);
  }
  if (b == 0 && threadIdx.x == 0) offs[NN] = 2 * NE;
}

// W packed: wP[j*68+k] = bf16(W1[k][j])<<16 | bf16(W0[k][j]).
__device__ __forceinline__ void stage_w_pk(const float* __restrict__ W0,
                                           const float* __restrict__ W1,
                                           unsigned* wP) {
  for (int i = threadIdx.x; i < 4096; i += 256) {
    int k = i >> 6, j = i & 63;
    wP[j * 68 + k] = (__float_as_uint(W1[i]) & 0xffff0000u) |
                     (__float_as_uint(W0[i]) >> 16);
  }
}

// fp8 encode: byte0 of cvt_pk_fp8_f32 (HW OCP e4m3 on gfx950)
__device__ __forceinline__ unsigned char f32_to_f8(float v) {
  return (unsigned char)(__builtin_amdgcn_cvt_pk_fp8_f32(v, v, 0, false) & 0xff);
}

#define ACC8(mvv)                                                   \
  do {                                                              \
    auto lo = __builtin_amdgcn_cvt_pk_f32_fp8((mvv), false);        \
    auto hi = __builtin_amdgcn_cvt_pk_f32_fp8((mvv), true);         \
    acc[0] += lo[0]; acc[1] += lo[1]; acc[2] += hi[0]; acc[3] += hi[1]; \
  } while (0)

// ---- quad-fp8 gather: row = 16 dwords (64 fp8 cols). lane = q*16+c.
// Clean 32-chunks with next-chunk idx prefetch; 16/8/pred-8 tail.
__device__ __forceinline__ float gather_row_q8(const unsigned* __restrict__ msgu,
                                               const int* __restrict__ nbr,
                                               int n0, int n1, int q, int c,
                                               int lane) {
  float acc[4] = {0.0f, 0.0f, 0.0f, 0.0f};
  int jb = n0;
  if (jb + 32 <= n1) {
    int idx[8];
#pragma unroll
    for (int u = 0; u < 8; ++u) idx[u] = nbr[jb + 4 * u + q];
    for (;;) {
      unsigned mv[8];
#pragma unroll
      for (int u = 0; u < 8; ++u) mv[u] = msgu[(idx[u] << 4) + c];
      const int jn = jb + 32;
      const bool more = (jn + 32 <= n1);
      if (more) {  // prefetch next chunk's indices under current row-loads
#pragma unroll
        for (int u = 0; u < 8; ++u) idx[u] = nbr[jn + 4 * u + q];
      }
#pragma unroll
      for (int u = 0; u < 8; ++u) ACC8(mv[u]);
      jb = jn;
      if (!more) break;
    }
  }
  if (jb + 16 <= n1) {  // clean 16-chunk
    int idx[4];
#pragma unroll
    for (int u = 0; u < 4; ++u) idx[u] = nbr[jb + 4 * u + q];
    unsigned mv[4];
#pragma unroll
    for (int u = 0; u < 4; ++u) mv[u] = msgu[(idx[u] << 4) + c];
#pragma unroll
    for (int u = 0; u < 4; ++u) ACC8(mv[u]);
    jb += 16;
  }
  if (jb + 8 <= n1) {  // clean 8-chunk
    int i0 = nbr[jb + q], i1 = nbr[jb + 4 + q];
    unsigned m0 = msgu[(i0 << 4) + c];
    unsigned m1 = msgu[(i1 << 4) + c];
    ACC8(m0);
    ACC8(m1);
    jb += 8;
  }
  if (jb < n1) {  // one predicated 8-chunk (remainder <= 7)
    int i0 = nbr[min(jb + q, n1 - 1)];
    int i1 = nbr[min(jb + 4 + q, n1 - 1)];
    unsigned m0 = msgu[(i0 << 4) + c];
    unsigned m1 = msgu[(i1 << 4) + c];
    if (jb + q >= n1) m0 = 0u;
    if (jb + 4 + q >= n1) m1 = 0u;
    ACC8(m0);
    ACC8(m1);
  }
#pragma unroll
  for (int k = 0; k < 4; ++k) {
    acc[k] += __shfl_xor(acc[k], 16, 64);
    acc[k] += __shfl_xor(acc[k], 32, 64);
  }
  float t0 = __shfl(acc[0], lane >> 2, 64);
  float t1 = __shfl(acc[1], lane >> 2, 64);
  float t2 = __shfl(acc[2], lane >> 2, 64);
  float t3 = __shfl(acc[3], lane >> 2, 64);
  const int s = lane & 3;
  return (s == 0) ? t0 : ((s == 1) ? t1 : ((s == 2) ? t2 : t3));
}

// ---- gemm core on a parked 8-row LDS batch, packed bf16 W pair in LDS
__device__ __forceinline__ void gemm_batch(const unsigned* wP,
                                           const float* myrows, int lane,
                                           float bv0, float bv1,
                                           float* a0, float* a1) {
#pragma unroll
  for (int rr = 0; rr < RB; ++rr) { a0[rr] = bv0; a1[rr] = bv1; }
#pragma unroll 1  // rolled: keeps W reads in LDS (no LICM VGPR blowup, R8/R9)
  for (int k4 = 0; k4 < 16; ++k4) {
    uint4 up = *reinterpret_cast<const uint4*>(&wP[lane * 68 + k4 * 4]);
    const float v0x = __uint_as_float(up.x << 16);
    const float v1x = __uint_as_float(up.x & 0xffff0000u);
    const float v0y = __uint_as_float(up.y << 16);
    const float v1y = __uint_as_float(up.y & 0xffff0000u);
    const float v0z = __uint_as_float(up.z << 16);
    const float v1z = __uint_as_float(up.z & 0xffff0000u);
    const float v0w = __uint_as_float(up.w << 16);
    const float v1w = __uint_as_float(up.w & 0xffff0000u);
#pragma unroll
    for (int rr = 0; rr < RB; ++rr) {
      float4 hv = *reinterpret_cast<const float4*>(&myrows[rr * 64 + k4 * 4]);
      a0[rr] = fmaf(hv.x, v0x, a0[rr]); a1[rr] = fmaf(hv.x, v1x, a1[rr]);
      a0[rr] = fmaf(hv.y, v0y, a0[rr]); a1[rr] = fmaf(hv.y, v1y, a1[rr]);
      a0[rr] = fmaf(hv.z, v0z, a0[rr]); a1[rr] = fmaf(hv.z, v1z, a1[rr]);
      a0[rr] = fmaf(hv.w, v0w, a0[rr]); a1[rr] = fmaf(hv.w, v1w, a1[rr]);
    }
  }
}

// ---- gemm2: base = h@W0+b0 (f32), msg = fp8(h@W1+b1)
__global__ __launch_bounds__(256) void k_gemm2(
    const float* __restrict__ h, const float* __restrict__ W0,
    const float* __restrict__ b0, const float* __restrict__ W1,
    const float* __restrict__ b1, float* __restrict__ base,
    unsigned char* __restrict__ msg, int nrows) {
  __shared__ unsigned wP[64 * 68];
  __shared__ float rbuf[4][RB * 64];
  stage_w_pk(W0, W1, wP);
  __syncthreads();
  const int lane = threadIdx.x & 63;
  const int wv = threadIdx.x >> 6;
  const int wid = (blockIdx.x * 256 + threadIdx.x) >> 6;
  const int nw = (gridDim.x * 256) >> 6;
  const float bv0 = b0[lane], bv1 = b1[lane];
  float* myrows = rbuf[wv];

  const int chunk = (nrows + nw - 1) / nw;
  const int r0 = wid * chunk;
  const int r1 = min(r0 + chunk, nrows);
  if (r0 >= nrows) return;

  float st[RB];
#pragma unroll
  for (int rr = 0; rr < RB; ++rr) {
    int r = min(r0 + rr, nrows - 1);
    st[rr] = h[(size_t)r * 64 + lane];
  }
  for (int rb = r0; rb < r1; rb += RB) {
#pragma unroll
    for (int rr = 0; rr < RB; ++rr) myrows[rr * 64 + lane] = st[rr];
    const int nb = rb + RB;
    if (nb < r1) {
#pragma unroll
      for (int rr = 0; rr < RB; ++rr) {
        int r = min(nb + rr, nrows - 1);
        st[rr] = h[(size_t)r * 64 + lane];
      }
    }
    float a0[RB], a1[RB];
    gemm_batch(wP, myrows, lane, bv0, bv1, a0, a1);
#pragma unroll
    for (int rr = 0; rr < RB; ++rr) {
      int r = rb + rr;
      if (r < r1) {
        base[(size_t)r * 64 + lane] = a0[rr];
        msg[(size_t)r * 64 + lane] = f32_to_f8(a1[rr]);
      }
    }
  }
}

// ---- aggLN: hout = ReLU(LN(base + gather(msg)/deg))   (un-fused gather phase;
// runs at the pure-gather operating point -- R20 split, aggF evidence)
__global__ __launch_bounds__(256) void k_aggLN(
    const float* __restrict__ base, const unsigned char* __restrict__ msg,
    const int* __restrict__ offs, const int* __restrict__ nbr,
    const float* __restrict__ gamma, const float* __restrict__ beta,
    float* __restrict__ hout, int nrows) {
  const int lane = threadIdx.x & 63;
  const int q = lane >> 4;
  const int c = lane & 15;
  const int wid = (blockIdx.x * 256 + threadIdx.x) >> 6;
  const int nw = (gridDim.x * 256) >> 6;
  const float gm = gamma[lane], bt = beta[lane];
  const unsigned* msgu = reinterpret_cast<const unsigned*>(msg);
  for (int r = wid; r < nrows; r += nw) {
    const int n0 = offs[r], n1 = offs[r + 1];
    const float bval = base[(size_t)r * 64 + lane];  // issued before gather
    float ag = gather_row_q8(msgu, nbr, n0, n1, q, c, lane);
    const float rdeg = 1.0f / fmaxf((float)(n1 - n0), 1.0f);
    float val = fmaf(ag, rdeg, bval);
    // LayerNorm (E[x^2]-mu^2, two trees interleaved) + ReLU
    float s = val, s2 = val * val;
#pragma unroll
    for (int off = 32; off > 0; off >>= 1) {
      s += __shfl_xor(s, off, 64);
      s2 += __shfl_xor(s2, off, 64);
    }
    const float mu = s * (1.0f / 64.0f);
    const float var = fmaxf(s2 * (1.0f / 64.0f) - mu * mu, 0.0f);
    const float dv = val - mu;
    val = fmaxf(fmaf(dv * rsqrtf(var + 1e-5f), gm, bt), 0.0f);
    hout[(size_t)r * 64 + lane] = val;
  }
}

// ---- final aggregation (layer 2, no LN): base += gather(msg)/deg, in place
__global__ __launch_bounds__(256) void k_aggF(
    float* __restrict__ base, const unsigned char* __restrict__ msg,
    const int* __restrict__ offs, const int* __restrict__ nbr, int nrows) {
  const int lane = threadIdx.x & 63;
  const int q = lane >> 4;
  const int c = lane & 15;
  const int wid = (blockIdx.x * 256 + threadIdx.x) >> 6;
  const int nw = (gridDim.x * 256) >> 6;
  const unsigned* msgu = reinterpret_cast<const unsigned*>(msg);
  for (int r = wid; r < nrows; r += nw) {
    const int n0 = offs[r], n1 = offs[r + 1];
    const float bval = base[(size_t)r * 64 + lane];
    float ag = gather_row_q8(msgu, nbr, n0, n1, q, c, lane);
    const float rdeg = 1.0f / fmaxf((float)(n1 - n0), 1.0f);
    base[(size_t)r * 64 + lane] = fmaf(ag, rdeg, bval);
  }
}

extern "C" void kernel_launch(void* const* d_in, const int* in_sizes, int n_in,
                              void* d_out, int out_size, void* d_ws, size_t ws_size,
                              hipStream_t stream) {
  const float* vert = (const float*)d_in[0];
  const int* edges = (const int*)d_in[1];
  const float* W0 = (const float*)d_in[2];
  const float* b0 = (const float*)d_in[3];
  const float* W1 = (const float*)d_in[4];
  const float* b1 = (const float*)d_in[5];
  const float* lng = (const float*)d_in[6];
  const float* lnb = (const float*)d_in[7];
  float* base = (float*)d_out;  // base lives in d_out all layers (in-place final)

  // ws layout (51.6 MB = proven capacity):
  //   nbr 12.8 | creg 12.8 (items during CSR; msgA 6.4 + msgB 6.4 after) |
  //   hbuf 25.6 (f32 h between aggLN and gemm2) | offs 0.4
  const size_t NBR_B = (size_t)2 * NE * 4;        // 12.8 MB
  const size_t MSG_B = (size_t)NN * 64;           // 6.4 MB (fp8)
  const size_t HB = (size_t)NN * 64 * 4;          // 25.6 MB
  int* nbr = (int*)d_ws;
  char* creg = (char*)d_ws + NBR_B;
  unsigned* items = (unsigned*)creg;              // 2*NE u32 = 12.8 MB
  unsigned char* msgA = (unsigned char*)creg;     // 6.4 MB
  unsigned char* msgB = (unsigned char*)(creg + MSG_B);  // 6.4 MB
  float* hbuf = (float*)(creg + NBR_B);           // 25.6 MB
  int* offs = (int*)((char*)hbuf + HB);           // NN+1 ints
  // CSR scan temporaries in d_out (dead before gemm2-L0 writes base)
  int* cnts = (int*)d_out;        // SCN ints
  int* sscan = cnts + SCN;        // SCN ints
  int* bsum = sscan + SCN;        // SCB ints

  // ---- CSR build: bucket sort, zero global atomics
  k_s1count<<<NB1, 256, 0, stream>>>(edges, cnts);
  k_scanA<<<SCB, 1024, 0, stream>>>(cnts, sscan, bsum, SCN);
  k_scanB<<<1, 256, 0, stream>>>(bsum, SCB);
  k_scanC<<<(SCN + 255) / 256, 256, 0, stream>>>(sscan, bsum, SCN);
  k_s1scatter<<<NB1, 256, 0, stream>>>(edges, sscan, items);
  k_s2build<<<NBUCK, 256, 0, stream>>>(items, sscan, offs, nbr);

  const int GG = 1536;   // gemm2 grid
  const int GA = 2048;   // agg grids

  // layer 0: vert -> base, msgA
  k_gemm2<<<GG, 256, 0, stream>>>(vert, W0, b0, W1, b1, base, msgA, NN);
  // agg(0)+LN0 -> hbuf ; gemm(1): hbuf -> base, msgB
  k_aggLN<<<GA, 256, 0, stream>>>(base, msgA, offs, nbr, lng, lnb, hbuf, NN);
  k_gemm2<<<GG, 256, 0, stream>>>(hbuf, W0 + 4096, b0 + 64,
                                  W1 + 4096, b1 + 64, base, msgB, NN);
  // agg(1)+LN1 -> hbuf ; gemm(2): hbuf -> base, msgA
  k_aggLN<<<GA, 256, 0, stream>>>(base, msgB, offs, nbr, lng + 64, lnb + 64,
                                  hbuf, NN);
  k_gemm2<<<GG, 256, 0, stream>>>(hbuf, W0 + 8192, b0 + 128,
                                  W1 + 8192, b1 + 128, base, msgA, NN);
  // final agg(2), no LN: base += gather(msgA)/deg  (in place -> d_out)
  k_aggF<<<GA, 256, 0, stream>>>(base, msgA, offs, nbr, NN);
}

// Round 21
// 367.623 us; speedup vs baseline: 1.2310x; 1.0135x over previous
//
#include <hip/hip_runtime.h>
#include <hip/hip_bf16.h>

constexpr int D_ = 64;
constexpr int NN = 100000;
constexpr int NE = 1600000;
constexpr int RB = 8;        // rows per wave-batch in gemm phase

// ---- sort-CSR parameters
constexpr int BUCK_SH = 7;                         // 128 nodes per bucket
constexpr int NBUCK = (NN + 127) >> BUCK_SH;       // 782
constexpr int NB1 = 256;                           // S1 grid
constexpr int NQ4 = NE / 4;                        // 400000 quads
constexpr int QPB = (NQ4 + NB1 - 1) / NB1;         // 1563 quads/block
constexpr int SCN = NBUCK * NB1;                   // 200192 count entries
constexpr int SCB = (SCN + 1023) / 1024;           // 196 scan blocks

// ---- S1A: per-block LDS histogram of endpoint buckets (no global atomics)
__global__ __launch_bounds__(256) void k_s1count(const int* __restrict__ edges,
                                                 int* __restrict__ cnts) {
  __shared__ int hist[NBUCK];
  for (int i = threadIdx.x; i < NBUCK; i += 256) hist[i] = 0;
  __syncthreads();
  const int q0 = blockIdx.x * QPB;
  const int q1 = min(q0 + QPB, NQ4);
  for (int q = q0 + (int)threadIdx.x; q < q1; q += 256) {
    const int4* ep = reinterpret_cast<const int4*>(edges + 8 * q);
    int4 a = ep[0], b = ep[1];
    atomicAdd(&hist[a.x >> BUCK_SH], 1);
    atomicAdd(&hist[a.y >> BUCK_SH], 1);
    atomicAdd(&hist[a.z >> BUCK_SH], 1);
    atomicAdd(&hist[a.w >> BUCK_SH], 1);
    atomicAdd(&hist[b.x >> BUCK_SH], 1);
    atomicAdd(&hist[b.y >> BUCK_SH], 1);
    atomicAdd(&hist[b.z >> BUCK_SH], 1);
    atomicAdd(&hist[b.w >> BUCK_SH], 1);
  }
  __syncthreads();
  for (int i = threadIdx.x; i < NBUCK; i += 256)
    cnts[i * NB1 + blockIdx.x] = hist[i];  // bucket-major for linear scan
}

// ---- hierarchical scan A (1024-wide blocks)
__global__ __launch_bounds__(1024) void k_scanA(const int* __restrict__ cnt,
                                                int* __restrict__ oscan,
                                                int* __restrict__ bsum, int n) {
  __shared__ int sd[1024];
  const int tid = threadIdx.x;
  const int i = blockIdx.x * 1024 + tid;
  int v = (i < n) ? cnt[i] : 0;
  sd[tid] = v;
  __syncthreads();
  for (int off = 1; off < 1024; off <<= 1) {
    int t = (tid >= off) ? sd[tid - off] : 0;
    __syncthreads();
    sd[tid] += t;
    __syncthreads();
  }
  if (i < n) oscan[i] = sd[tid] - v;
  if (tid == 1023) bsum[blockIdx.x] = sd[1023];
}

// ---- scan B: single 256-thread block scans block totals (exclusive, in place)
__global__ __launch_bounds__(256) void k_scanB(int* __restrict__ bsum, int nb) {
  __shared__ int sd[256];
  const int tid = threadIdx.x;
  int v = (tid < nb) ? bsum[tid] : 0;
  sd[tid] = v;
  __syncthreads();
  for (int off = 1; off < 256; off <<= 1) {
    int t = (tid >= off) ? sd[tid - off] : 0;
    __syncthreads();
    sd[tid] += t;
    __syncthreads();
  }
  if (tid < nb) bsum[tid] = sd[tid] - v;
}

// ---- scan C: add block base
__global__ __launch_bounds__(256) void k_scanC(int* __restrict__ oscan,
                                               const int* __restrict__ bsum, int n) {
  int i = blockIdx.x * 256 + threadIdx.x;
  if (i < n) oscan[i] += bsum[i >> 10];
}

// ---- S1B: scatter items into bucket-sorted array via LDS cursors.
__global__ __launch_bounds__(256) void k_s1scatter(const int* __restrict__ edges,
                                                   const int* __restrict__ sscan,
                                                   unsigned* __restrict__ items) {
  __shared__ int cur[NBUCK];
  for (int i = threadIdx.x; i < NBUCK; i += 256)
    cur[i] = sscan[i * NB1 + blockIdx.x];
  __syncthreads();
  const int q0 = blockIdx.x * QPB;
  const int q1 = min(q0 + QPB, NQ4);
  for (int q = q0 + (int)threadIdx.x; q < q1; q += 256) {
    const int4* ep = reinterpret_cast<const int4*>(edges + 8 * q);
    int4 a = ep[0], b = ep[1];
    int p;
    p = atomicAdd(&cur[a.y >> BUCK_SH], 1); items[p] = ((unsigned)(a.y & 127) << 17) | (unsigned)a.x;
    p = atomicAdd(&cur[a.x >> BUCK_SH], 1); items[p] = ((unsigned)(a.x & 127) << 17) | (unsigned)a.y;
    p = atomicAdd(&cur[a.w >> BUCK_SH], 1); items[p] = ((unsigned)(a.w & 127) << 17) | (unsigned)a.z;
    p = atomicAdd(&cur[a.z >> BUCK_SH], 1); items[p] = ((unsigned)(a.z & 127) << 17) | (unsigned)a.w;
    p = atomicAdd(&cur[b.y >> BUCK_SH], 1); items[p] = ((unsigned)(b.y & 127) << 17) | (unsigned)b.x;
    p = atomicAdd(&cur[b.x >> BUCK_SH], 1); items[p] = ((unsigned)(b.x & 127) << 17) | (unsigned)b.y;
    p = atomicAdd(&cur[b.w >> BUCK_SH], 1); items[p] = ((unsigned)(b.w & 127) << 17) | (unsigned)b.z;
    p = atomicAdd(&cur[b.z >> BUCK_SH], 1); items[p] = ((unsigned)(b.z & 127) << 17) | (unsigned)b.w;
  }
}

// ---- S2: one block per bucket -> local histogram+scan -> offs + nbr placement
__global__ __launch_bounds__(256) void k_s2build(const unsigned* __restrict__ items,
                                                 const int* __restrict__ sscan,
                                                 int* __restrict__ offs,
                                                 int* __restrict__ nbr) {
  const int b = blockIdx.x;
  const int lo = b << BUCK_SH;
  __shared__ int hist[128], scn[128];
  __shared__ int sbase, send;
  if (threadIdx.x == 0) {
    sbase = sscan[b * NB1];
    send = (b + 1 < NBUCK) ? sscan[(b + 1) * NB1] : 2 * NE;
  }
  if (threadIdx.x < 128) hist[threadIdx.x] = 0;
  __syncthreads();
  const int i0 = sbase, i1 = send;
  for (int i = i0 + (int)threadIdx.x; i < i1; i += 256)
    atomicAdd(&hist[items[i] >> 17], 1);
  __syncthreads();
  if (threadIdx.x < 128) scn[threadIdx.x] = hist[threadIdx.x];
  __syncthreads();
  for (int off = 1; off < 128; off <<= 1) {
    int t = (threadIdx.x < 128 && (int)threadIdx.x >= off) ? scn[threadIdx.x - off] : 0;
    __syncthreads();
    if (threadIdx.x < 128) scn[threadIdx.x] += t;
    __syncthreads();
  }
  if (threadIdx.x < 128) {
    int node = lo + threadIdx.x;
    int ex = sbase + scn[threadIdx.x] - hist[threadIdx.x];
    if (node < NN) offs[node] = ex;
    hist[threadIdx.x] = ex;  // placement cursor
  }
  __syncthreads();
  for (int i = i0 + (int)threadIdx.x; i < i1; i += 256) {
    unsigned it = items[i];
    int pos = atomicAdd(&hist[it >> 17], 1);
    nbr[pos] = (int)(it & 0x1FFFFu);
  }
  if (b == 0 && threadIdx.x == 0) offs[NN] = 2 * NE;
}

// W staged transposed+padded: wT[j*68+k] = W[k*64+j]
__device__ __forceinline__ void stage_w(const float* __restrict__ W, float* wT) {
  for (int i = threadIdx.x; i < 4096; i += 256) {
    int k = i >> 6, j = i & 63;
    wT[j * 68 + k] = W[i];
  }
}

// fp8 encode: byte0 of cvt_pk_fp8_f32 (HW OCP e4m3 on gfx950)
__device__ __forceinline__ unsigned char f32_to_f8(float v) {
  return (unsigned char)(__builtin_amdgcn_cvt_pk_fp8_f32(v, v, 0, false) & 0xff);
}

// ---- quad-fp8 gather: row = 16 dwords (64 fp8 cols). lane = q*16+c:
// q = neighbor slot (4 rows per load instr), c = dword (cols 4c..4c+3).
// 32-neighbor chunks: 8 loads, 8x(2 cvt + 4 add) VALU.
__device__ __forceinline__ float gather_row_q8(const unsigned* __restrict__ msgu,
                                               const int* __restrict__ nbr,
                                               int n0, int n1, int q, int c,
                                               int lane) {
  float acc[4] = {0.0f, 0.0f, 0.0f, 0.0f};
  int jb = n0;
  for (; jb + 32 <= n1; jb += 32) {  // clean chunks
    int idx[8];
#pragma unroll
    for (int u = 0; u < 8; ++u) idx[u] = nbr[jb + 4 * u + q];
    unsigned mv[8];
#pragma unroll
    for (int u = 0; u < 8; ++u) mv[u] = msgu[(idx[u] << 4) + c];
#pragma unroll
    for (int u = 0; u < 8; ++u) {
      auto lo = __builtin_amdgcn_cvt_pk_f32_fp8(mv[u], false);
      auto hi = __builtin_amdgcn_cvt_pk_f32_fp8(mv[u], true);
      acc[0] += lo[0]; acc[1] += lo[1]; acc[2] += hi[0]; acc[3] += hi[1];
    }
  }
  if (jb < n1) {  // one predicated chunk (clamped idx -> hot line; zeroed pad)
    int idx[8];
#pragma unroll
    for (int u = 0; u < 8; ++u) idx[u] = nbr[min(jb + 4 * u + q, n1 - 1)];
    unsigned mv[8];
#pragma unroll
    for (int u = 0; u < 8; ++u) mv[u] = msgu[(idx[u] << 4) + c];
#pragma unroll
    for (int u = 0; u < 8; ++u) {
      if (jb + 4 * u + q >= n1) mv[u] = 0u;  // fp8 0x00 == +0
      auto lo = __builtin_amdgcn_cvt_pk_f32_fp8(mv[u], false);
      auto hi = __builtin_amdgcn_cvt_pk_f32_fp8(mv[u], true);
      acc[0] += lo[0]; acc[1] += lo[1]; acc[2] += hi[0]; acc[3] += hi[1];
    }
  }
#pragma unroll
  for (int k = 0; k < 4; ++k) {
    acc[k] += __shfl_xor(acc[k], 16, 64);
    acc[k] += __shfl_xor(acc[k], 32, 64);
  }
  float t0 = __shfl(acc[0], lane >> 2, 64);
  float t1 = __shfl(acc[1], lane >> 2, 64);
  float t2 = __shfl(acc[2], lane >> 2, 64);
  float t3 = __shfl(acc[3], lane >> 2, 64);
  const int s = lane & 3;
  return (s == 0) ? t0 : ((s == 1) ? t1 : ((s == 2) ? t2 : t3));
}

// ---- gemm2: base = h@W0+b0 (f32), msg = fp8(h@W1+b1). (layer 0 only)
// k4 loop rolled (#pragma unroll 1): prevents LICM VGPR blowup (R8/R9).
__global__ __launch_bounds__(256) void k_gemm2(
    const float* __restrict__ h, const float* __restrict__ W0,
    const float* __restrict__ b0, const float* __restrict__ W1,
    const float* __restrict__ b1, float* __restrict__ base,
    unsigned char* __restrict__ msg, int nrows) {
  __shared__ float w0T[64 * 68];
  __shared__ float w1T[64 * 68];
  __shared__ float rbuf[4][RB * 64];
  stage_w(W0, w0T);
  stage_w(W1, w1T);
  __syncthreads();
  const int lane = threadIdx.x & 63;
  const int wv = threadIdx.x >> 6;
  const int wid = (blockIdx.x * 256 + threadIdx.x) >> 6;
  const int nw = (gridDim.x * 256) >> 6;
  const float bv0 = b0[lane], bv1 = b1[lane];
  const float4* wl0 = reinterpret_cast<const float4*>(&w0T[lane * 68]);
  const float4* wl1 = reinterpret_cast<const float4*>(&w1T[lane * 68]);
  float* myrows = rbuf[wv];

  const int chunk = (nrows + nw - 1) / nw;
  const int r0 = wid * chunk;
  const int r1 = min(r0 + chunk, nrows);
  if (r0 >= nrows) return;

  float st[RB];
#pragma unroll
  for (int rr = 0; rr < RB; ++rr) {
    int r = min(r0 + rr, nrows - 1);
    st[rr] = h[(size_t)r * 64 + lane];
  }
  for (int rb = r0; rb < r1; rb += RB) {
#pragma unroll
    for (int rr = 0; rr < RB; ++rr) myrows[rr * 64 + lane] = st[rr];
    const int nb = rb + RB;
    if (nb < r1) {
#pragma unroll
      for (int rr = 0; rr < RB; ++rr) {
        int r = min(nb + rr, nrows - 1);
        st[rr] = h[(size_t)r * 64 + lane];
      }
    }
    float a0[RB], a1[RB];
#pragma unroll
    for (int rr = 0; rr < RB; ++rr) { a0[rr] = bv0; a1[rr] = bv1; }
#pragma unroll 1
    for (int k4 = 0; k4 < 16; ++k4) {
      const float4 v0 = wl0[k4];
      const float4 v1 = wl1[k4];
#pragma unroll
      for (int rr = 0; rr < RB; ++rr) {
        float4 hv = *reinterpret_cast<const float4*>(&myrows[rr * 64 + k4 * 4]);
        a0[rr] = fmaf(hv.x, v0.x, a0[rr]); a1[rr] = fmaf(hv.x, v1.x, a1[rr]);
        a0[rr] = fmaf(hv.y, v0.y, a0[rr]); a1[rr] = fmaf(hv.y, v1.y, a1[rr]);
        a0[rr] = fmaf(hv.z, v0.z, a0[rr]); a1[rr] = fmaf(hv.z, v1.z, a1[rr]);
        a0[rr] = fmaf(hv.w, v0.w, a0[rr]); a1[rr] = fmaf(hv.w, v1.w, a1[rr]);
      }
    }
#pragma unroll
    for (int rr = 0; rr < RB; ++rr) {
      int r = rb + rr;
      if (r < r1) {
        base[(size_t)r * 64 + lane] = a0[rr];
        msg[(size_t)r * 64 + lane] = f32_to_f8(a1[rr]);
      }
    }
  }
}

// ---- fused: agg(l) [+LN+ReLU] then gemm2(l+1), h row never touches global.
__global__ __launch_bounds__(256) void k_fused(
    float* __restrict__ base, const unsigned char* __restrict__ msgin,
    unsigned char* __restrict__ msgout,
    const int* __restrict__ offs, const int* __restrict__ nbr,
    const float* __restrict__ gamma, const float* __restrict__ beta,
    const float* __restrict__ W0n, const float* __restrict__ b0n,
    const float* __restrict__ W1n, const float* __restrict__ b1n, int nrows) {
  __shared__ float w0T[64 * 68];
  __shared__ float w1T[64 * 68];
  __shared__ float rbuf[4][RB * 64];
  stage_w(W0n, w0T);
  stage_w(W1n, w1T);
  __syncthreads();
  const int lane = threadIdx.x & 63;
  const int wv = threadIdx.x >> 6;
  const int q = lane >> 4;
  const int c = lane & 15;
  const int wid = (blockIdx.x * 256 + threadIdx.x) >> 6;
  const int nw = (gridDim.x * 256) >> 6;
  const float gm = gamma[lane], bt = beta[lane];
  const float bv0 = b0n[lane], bv1 = b1n[lane];
  const float4* wl0 = reinterpret_cast<const float4*>(&w0T[lane * 68]);
  const float4* wl1 = reinterpret_cast<const float4*>(&w1T[lane * 68]);
  float* myrows = rbuf[wv];
  const unsigned* msgu = reinterpret_cast<const unsigned*>(msgin);

  const int chunk = (nrows + nw - 1) / nw;
  const int r0 = wid * chunk;
  const int r1 = min(r0 + chunk, nrows);
  if (r0 >= nrows) return;

  for (int rb = r0; rb < r1; rb += RB) {
#pragma unroll 1
    for (int rr = 0; rr < RB; ++rr) {
      int r = rb + rr;
      if (r >= r1) break;  // wave-uniform
      const int n0 = offs[r], n1 = offs[r + 1];
      const float bval = base[(size_t)r * 64 + lane];
      float ag = gather_row_q8(msgu, nbr, n0, n1, q, c, lane);
      const float rdeg = 1.0f / fmaxf((float)(n1 - n0), 1.0f);
      float val = fmaf(ag, rdeg, bval);
      // LayerNorm + ReLU
      float s = val;
#pragma unroll
      for (int off = 32; off > 0; off >>= 1) s += __shfl_xor(s, off, 64);
      const float mu = s * (1.0f / 64.0f);
      const float dv = val - mu;
      float v2 = dv * dv;
#pragma unroll
      for (int off = 32; off > 0; off >>= 1) v2 += __shfl_xor(v2, off, 64);
      const float var = v2 * (1.0f / 64.0f);
      val = fmaxf(fmaf(dv * rsqrtf(var + 1e-5f), gm, bt), 0.0f);
      myrows[rr * 64 + lane] = val;  // park h(l+1) row in LDS
    }
    // next-layer gemm on parked batch
    float a0[RB], a1[RB];
#pragma unroll
    for (int rr = 0; rr < RB; ++rr) { a0[rr] = bv0; a1[rr] = bv1; }
#pragma unroll 1
    for (int k4 = 0; k4 < 16; ++k4) {
      const float4 v0 = wl0[k4];
      const float4 v1 = wl1[k4];
#pragma unroll
      for (int rr = 0; rr < RB; ++rr) {
        float4 hv = *reinterpret_cast<const float4*>(&myrows[rr * 64 + k4 * 4]);
        a0[rr] = fmaf(hv.x, v0.x, a0[rr]); a1[rr] = fmaf(hv.x, v1.x, a1[rr]);
        a0[rr] = fmaf(hv.y, v0.y, a0[rr]); a1[rr] = fmaf(hv.y, v1.y, a1[rr]);
        a0[rr] = fmaf(hv.z, v0.z, a0[rr]); a1[rr] = fmaf(hv.z, v1.z, a1[rr]);
        a0[rr] = fmaf(hv.w, v0.w, a0[rr]); a1[rr] = fmaf(hv.w, v1.w, a1[rr]);
      }
    }
#pragma unroll
    for (int rr = 0; rr < RB; ++rr) {
      int r = rb + rr;
      if (r < r1) {
        base[(size_t)r * 64 + lane] = a0[rr];
        msgout[(size_t)r * 64 + lane] = f32_to_f8(a1[rr]);
      }
    }
  }
}

// ---- final aggregation (layer 2, no LN): base += gather(msg)/deg, in place
__global__ __launch_bounds__(256) void k_aggF(
    float* __restrict__ base, const unsigned char* __restrict__ msg,
    const int* __restrict__ offs, const int* __restrict__ nbr, int nrows) {
  const int lane = threadIdx.x & 63;
  const int q = lane >> 4;
  const int c = lane & 15;
  const int wid = (blockIdx.x * 256 + threadIdx.x) >> 6;
  const int nw = (gridDim.x * 256) >> 6;
  const unsigned* msgu = reinterpret_cast<const unsigned*>(msg);
  for (int r = wid; r < nrows; r += nw) {
    const int n0 = offs[r], n1 = offs[r + 1];
    const float bval = base[(size_t)r * 64 + lane];
    float ag = gather_row_q8(msgu, nbr, n0, n1, q, c, lane);
    const float rdeg = 1.0f / fmaxf((float)(n1 - n0), 1.0f);
    base[(size_t)r * 64 + lane] = fmaf(ag, rdeg, bval);
  }
}

extern "C" void kernel_launch(void* const* d_in, const int* in_sizes, int n_in,
                              void* d_out, int out_size, void* d_ws, size_t ws_size,
                              hipStream_t stream) {
  const float* vert = (const float*)d_in[0];
  const int* edges = (const int*)d_in[1];
  const float* W0 = (const float*)d_in[2];
  const float* b0 = (const float*)d_in[3];
  const float* W1 = (const float*)d_in[4];
  const float* b1 = (const float*)d_in[5];
  const float* lng = (const float*)d_in[6];
  const float* lnb = (const float*)d_in[7];
  float* base = (float*)d_out;  // base lives in d_out all layers (in-place updates)

  // ws layout: nbr 12.8 | creg 12.8 (items during CSR build; then msgA 6.4 + msgB 6.4) | offs
  const size_t NBR_B = (size_t)2 * NE * 4;        // 12.8 MB
  const size_t MSG_B = (size_t)NN * 64;           // 6.4 MB (fp8)
  int* nbr = (int*)d_ws;
  char* creg = (char*)d_ws + NBR_B;
  unsigned* items = (unsigned*)creg;              // 2*NE u32 = 12.8 MB
  unsigned char* msgA = (unsigned char*)creg;     // 6.4 MB
  unsigned char* msgB = (unsigned char*)(creg + MSG_B);  // 6.4 MB
  int* offs = (int*)(creg + NBR_B);               // persistent, NN+1 ints
  // CSR scan temporaries in d_out (dead before gemm2-L0 writes base)
  int* cnts = (int*)d_out;        // SCN ints
  int* sscan = cnts + SCN;        // SCN ints
  int* bsum = sscan + SCN;        // SCB ints

  // ---- CSR build: bucket sort, zero global atomics
  k_s1count<<<NB1, 256, 0, stream>>>(edges, cnts);
  k_scanA<<<SCB, 1024, 0, stream>>>(cnts, sscan, bsum, SCN);
  k_scanB<<<1, 256, 0, stream>>>(bsum, SCB);
  k_scanC<<<(SCN + 255) / 256, 256, 0, stream>>>(sscan, bsum, SCN);
  k_s1scatter<<<NB1, 256, 0, stream>>>(edges, sscan, items);
  k_s2build<<<NBUCK, 256, 0, stream>>>(items, sscan, offs, nbr);

  const int GG = 1536;   // gemm2 grid
  const int GF = 768;    // fused grid: 3 blocks/CU (43 KB LDS)
  const int GA = 2048;   // final agg grid

  // layer 0 gemms: vert -> base(d_out), msgA
  k_gemm2<<<GG, 256, 0, stream>>>(vert, W0, b0, W1, b1, base, msgA, NN);
  // fused agg(0)+LN0+gemm(1): base,msgA -> base,msgB
  k_fused<<<GF, 256, 0, stream>>>(base, msgA, msgB, offs, nbr,
                                  lng, lnb, W0 + 4096, b0 + 64,
                                  W1 + 4096, b1 + 64, NN);
  // fused agg(1)+LN1+gemm(2): base,msgB -> base,msgA
  k_fused<<<GF, 256, 0, stream>>>(base, msgB, msgA, offs, nbr,
                                  lng + 64, lnb + 64, W0 + 8192, b0 + 128,
                                  W1 + 8192, b1 + 128, NN);
  // final agg(2), no LN: base += gather(msgA)/deg  (in place -> d_out)
  k_aggF<<<GA, 256, 0, stream>>>(base, msgA, offs, nbr, NN);
}